// Round 9
// baseline (271.009 us; speedup 1.0000x reference)
//
#include <hip/hip_runtime.h>
#include <float.h>

#define BB 4
#define PP 1024
#define DD 1024
#define RR 256
#define SSZ 256
#define KT 4
#define EE 4096
#define NPAIR 3

typedef float  f32x4  __attribute__((ext_vector_type(4)));
typedef short  short8 __attribute__((ext_vector_type(8)));

#define MFMA16(a,b,c) __builtin_amdgcn_mfma_f32_16x16x32_bf16((a),(b),(c),0,0,0)

// ---- float-region offsets (in floats) ----
#define OFF_NE    ((size_t)0)         // BB*EE
#define OFF_RR_T  ((size_t)16384)     // BB*RR
#define OFF_RR_S  ((size_t)17408)
#define OFF_HH    ((size_t)18432)     // BB*RR*KT
#define OFF_RH_T  ((size_t)22528)
#define OFF_RH_S  ((size_t)26624)
#define OFF_SS_T  ((size_t)30720)     // NPAIR*BB*SSZ
#define OFF_SS_S  ((size_t)33792)
#define OFF_TOPK  ((size_t)36864)     // BB*RR*KT ints
#define OFF_ACC   ((size_t)40960)     // double (8B aligned)
#define OFF_SIM   ((size_t)45056)     // BB*RR*EE floats (16B aligned)
#define FLOAT_END ((size_t)4239360)   // = OFF_SIM + 4194304

// ---- ushort (bf16) region offsets (in ushorts), base = ws + FLOAT_END ----
#define U_REF_T_HI ((size_t)0)        // BB*RR*DD
#define U_REF_S_HI ((size_t)2097152)
#define U_SIMH_HI  ((size_t)4194304)  // BB*RR*KT*DD
#define REF_DELTA  ((size_t)1048576)  // hi -> lo distance for ref arrays
#define SIMH_DELTA ((size_t)4194304)  // hi -> lo distance for simh
#define U_SH_T_HI  ((size_t)12582912) // NPAIR*BB*SSZ*DD each
#define U_SH_T_LO  ((size_t)15728640)
#define U_SH_S_HI  ((size_t)18874368)
#define U_SH_S_LO  ((size_t)22020096)
// ushort region end = 25165824 (50.3 MB); total ws ~67.3 MB

__device__ inline float block_sum256(float v, float* sb) {
  v += __shfl_down(v, 32); v += __shfl_down(v, 16);
  v += __shfl_down(v, 8);  v += __shfl_down(v, 4);
  v += __shfl_down(v, 2);  v += __shfl_down(v, 1);
  int lane = threadIdx.x & 63, wid = threadIdx.x >> 6;
  if (lane == 0) sb[wid] = v;
  __syncthreads();
  float r = 0.f;
  if (threadIdx.x < 4) r = sb[threadIdx.x];
  r += __shfl_down(r, 2); r += __shfl_down(r, 1);
  __syncthreads();
  return r;   // valid on thread 0
}

__device__ inline float dot4(const float4& a, const float4& b) {
  return a.x*b.x + a.y*b.y + a.z*b.z + a.w*b.w;
}

// round-to-nearest-even split: x = hi + lo (both bf16), |err| ~ 2^-16 |x|
__device__ inline ushort2 bsplit(float x) {
  unsigned u = __float_as_uint(x);
  unsigned hb = (u + 0x7fffu + ((u >> 16) & 1u)) & 0xffff0000u;
  float lo = x - __uint_as_float(hb);
  unsigned ul = __float_as_uint(lo);
  unsigned lb = (ul + 0x7fffu + ((ul >> 16) & 1u)) >> 16;
  return make_ushort2((unsigned short)(hb >> 16), (unsigned short)lb);
}

__device__ inline void split4(float4 f, ushort4& h, ushort4& l) {
  ushort2 t0 = bsplit(f.x), t1 = bsplit(f.y), t2 = bsplit(f.z), t3 = bsplit(f.w);
  h = make_ushort4(t0.x, t1.x, t2.x, t3.x);
  l = make_ushort4(t0.y, t1.y, t2.y, t3.y);
}

__device__ inline void split8(const float* p, uint4& h, uint4& l) {
  float4 f0 = *(const float4*)p;
  float4 f1 = *(const float4*)(p + 4);
  ushort2 t0 = bsplit(f0.x), t1 = bsplit(f0.y), t2 = bsplit(f0.z), t3 = bsplit(f0.w);
  ushort2 t4 = bsplit(f1.x), t5 = bsplit(f1.y), t6 = bsplit(f1.z), t7 = bsplit(f1.w);
  h.x = (unsigned)t0.x | ((unsigned)t1.x << 16); h.y = (unsigned)t2.x | ((unsigned)t3.x << 16);
  h.z = (unsigned)t4.x | ((unsigned)t5.x << 16); h.w = (unsigned)t6.x | ((unsigned)t7.x << 16);
  l.x = (unsigned)t0.y | ((unsigned)t1.y << 16); l.y = (unsigned)t2.y | ((unsigned)t3.y << 16);
  l.z = (unsigned)t4.y | ((unsigned)t5.y << 16); l.w = (unsigned)t6.y | ((unsigned)t7.y << 16);
}

// ---- gather ref rows: norms + bf16 hi/lo split store ----
__global__ __launch_bounds__(256) void k_gather_ref(const float* __restrict__ T,
                                                    const float* __restrict__ Sf,
                                                    const int* __restrict__ ref_perm,
                                                    float* __restrict__ ws) {
  __shared__ float sb[4];
  int b = blockIdx.x >> 8, r = blockIdx.x & 255;
  int pos = ref_perm[r];
  const float4* ts = (const float4*)(T  + ((size_t)(b*8 + 0)*PP + pos)*DD);
  const float4* sv = (const float4*)(Sf + ((size_t)(b*4 + 0)*PP + pos)*DD);
  ushort* uws = (ushort*)(ws + FLOAT_END);
  int t = threadIdx.x;                    // DD/4 == 256
  float4 a = ts[t], c = sv[t];
  size_t base = ((size_t)b*RR + r)*DD + t*4;
  ushort4 h4, l4;
  split4(a, h4, l4);
  *(ushort4*)(uws + U_REF_T_HI + base) = h4;
  *(ushort4*)(uws + U_REF_T_HI + REF_DELTA + base) = l4;
  split4(c, h4, l4);
  *(ushort4*)(uws + U_REF_S_HI + base) = h4;
  *(ushort4*)(uws + U_REF_S_HI + REF_DELTA + base) = l4;
  float r1 = block_sum256(dot4(a, a), sb);
  float r2 = block_sum256(dot4(c, c), sb);
  if (t == 0) {
    ws[OFF_RR_T + b*RR + r] = r1;
    ws[OFF_RR_S + b*RR + r] = r2;
  }
}

// ---- clamped norms of extra_t rows ----
__global__ __launch_bounds__(256) void k_ne(const float* __restrict__ T, float* __restrict__ ws) {
  __shared__ float sb[4];
  int b = blockIdx.x >> 12, e = blockIdx.x & 4095;
  int f = 1 + 2*(e >> 10);
  int pos = e & 1023;
  const float4* src = (const float4*)(T + ((size_t)(b*8 + f)*PP + pos)*DD);
  float4 a = src[threadIdx.x];
  float tot = block_sum256(dot4(a, a), sb);
  if (threadIdx.x == 0) ws[OFF_NE + (size_t)b*EE + e] = fmaxf(sqrtf(tot), 1e-12f);
}

// ---- shared rows: norms + bf16 hi/lo pre-split store (teacher + student) ----
__global__ __launch_bounds__(256) void k_ss(const float* __restrict__ T,
                                            const float* __restrict__ Sf,
                                            const int* __restrict__ shared_perm,
                                            float* __restrict__ ws) {
  __shared__ float sb[4];
  int idx = blockIdx.x;                  // z*SSZ + s, z = p*BB+b
  int p = idx / (BB*SSZ);
  int b = (idx / SSZ) % BB;
  int s = idx % SSZ;
  int pos = shared_perm[s];
  int ti = 2*(p + 1), si = p + 1;
  const float4* tr = (const float4*)(T  + ((size_t)(b*8 + ti)*PP + pos)*DD);
  const float4* sr = (const float4*)(Sf + ((size_t)(b*4 + si)*PP + pos)*DD);
  ushort* uws = (ushort*)(ws + FLOAT_END);
  int t = threadIdx.x;
  float4 a = tr[t], c = sr[t];
  size_t base = (size_t)idx*DD + t*4;
  ushort4 h4, l4;
  split4(a, h4, l4);
  *(ushort4*)(uws + U_SH_T_HI + base) = h4;
  *(ushort4*)(uws + U_SH_T_LO + base) = l4;
  split4(c, h4, l4);
  *(ushort4*)(uws + U_SH_S_HI + base) = h4;
  *(ushort4*)(uws + U_SH_S_LO + base) = l4;
  float r1 = block_sum256(dot4(a, a), sb);
  float r2 = block_sum256(dot4(c, c), sb);
  if (t == 0) { ws[OFF_SS_T + idx] = r1; ws[OFF_SS_S + idx] = r2; }
}

// ---- sim GEMM (MFMA bf16 hi/lo): sim[b,r,e] = dot(ref_t, extra_e)/ne[e] ----
__global__ __launch_bounds__(256) void k_sim(const float* __restrict__ T, float* __restrict__ ws) {
  __shared__ ushort Ah[64][40];
  __shared__ ushort Al[64][40];
  __shared__ ushort Bh[64][40];
  __shared__ ushort Bl[64][40];
  ushort* uws = (ushort*)(ws + FLOAT_END);
  int e0 = blockIdx.x * 64, r0 = blockIdx.y * 64, b = blockIdx.z;
  int tid = threadIdx.x;
  int srow = tid >> 2, sch = tid & 3;
  const ushort* pAh = uws + U_REF_T_HI + ((size_t)(b*RR + r0 + srow))*DD + sch*8;
  int e = e0 + srow;
  const float* pB = T + ((size_t)(b*8 + 1 + 2*(e >> 10))*PP + (e & 1023))*DD + sch*8;
  int w = tid >> 6, l15 = tid & 15, lq = (tid >> 4) & 3, lk8 = lq*8;
  f32x4 acc[4];
#pragma unroll
  for (int j = 0; j < 4; ++j) acc[j] = (f32x4){0.f, 0.f, 0.f, 0.f};

#pragma unroll 1
  for (int k0 = 0; k0 < DD; k0 += 32) {
    uint4 vah = *(const uint4*)(pAh + k0);
    uint4 valo = *(const uint4*)(pAh + REF_DELTA + k0);
    uint4 bhv, blv;
    split8(pB + k0, bhv, blv);
    __syncthreads();
    *(uint4*)&Ah[srow][sch*8] = vah;
    *(uint4*)&Al[srow][sch*8] = valo;
    *(uint4*)&Bh[srow][sch*8] = bhv;
    *(uint4*)&Bl[srow][sch*8] = blv;
    __syncthreads();
    short8 ah = *(const short8*)&Ah[w*16 + l15][lk8];
    short8 al = *(const short8*)&Al[w*16 + l15][lk8];
#pragma unroll
    for (int j = 0; j < 4; ++j) {
      short8 bh = *(const short8*)&Bh[j*16 + l15][lk8];
      short8 bl = *(const short8*)&Bl[j*16 + l15][lk8];
      acc[j] = MFMA16(ah, bh, acc[j]);
      acc[j] = MFMA16(ah, bl, acc[j]);
      acc[j] = MFMA16(al, bh, acc[j]);
    }
  }
#pragma unroll
  for (int j = 0; j < 4; ++j) {
    int ee = e0 + j*16 + l15;
    float inv = 1.f / ws[OFF_NE + (size_t)b*EE + ee];
#pragma unroll
    for (int q = 0; q < 4; ++q) {
      int row = r0 + w*16 + lq*4 + q;
      ws[OFF_SIM + ((size_t)(b*RR + row) << 12) + ee] = acc[j][q] * inv;
    }
  }
}

// ---- top-4 per (b,r), stable (ties -> lower index) ----
__global__ __launch_bounds__(256) void k_topk(float* __restrict__ ws) {
  __shared__ float vals[EE];
  __shared__ float rv[256];
  __shared__ int   ri[256];
  int b = blockIdx.x >> 8, r = blockIdx.x & 255;
  const float* srow = ws + OFF_SIM + ((size_t)(b*RR + r))*EE;
  int tid = threadIdx.x;
#pragma unroll
  for (int i = 0; i < 16; ++i) vals[i*256 + tid] = srow[i*256 + tid];
  __syncthreads();
  int* outi = (int*)(ws + OFF_TOPK) + ((size_t)(b*RR + r))*KT;
  for (int k = 0; k < KT; ++k) {
    float bv = -FLT_MAX; int bi = 0x7fffffff;
#pragma unroll
    for (int i = 0; i < 16; ++i) {
      int e = i*256 + tid;
      float v = vals[e];
      if (v > bv || (v == bv && e < bi)) { bv = v; bi = e; }
    }
    rv[tid] = bv; ri[tid] = bi;
    __syncthreads();
    for (int off = 128; off > 0; off >>= 1) {
      if (tid < off) {
        float v2 = rv[tid+off]; int i2 = ri[tid+off];
        if (v2 > rv[tid] || (v2 == rv[tid] && i2 < ri[tid])) { rv[tid] = v2; ri[tid] = i2; }
      }
      __syncthreads();
    }
    if (tid == 0) { outi[k] = ri[0]; vals[ri[0]] = -FLT_MAX; }
    __syncthreads();
  }
}

// ---- gather selected rows: bf16 hi/lo store + hh / rh_t / rh_s (fp32) ----
__global__ __launch_bounds__(256) void k_gather_high(const float* __restrict__ T,
                                                     const float* __restrict__ Sf,
                                                     const int* __restrict__ ref_perm,
                                                     float* __restrict__ ws) {
  __shared__ float sb[4];
  int idx = blockIdx.x;                        // (b*RR + r)*KT + k
  int e = ((const int*)(ws + OFF_TOPK))[idx];
  int b = idx >> 10;
  int r = (idx >> 2) & 255;
  int rpos = ref_perm[r];
  const float4* src = (const float4*)(T + ((size_t)(b*8 + 1 + 2*(e >> 10))*PP + (e & 1023))*DD);
  const float4* rt  = (const float4*)(T  + ((size_t)(b*8 + 0)*PP + rpos)*DD);
  const float4* rs  = (const float4*)(Sf + ((size_t)(b*4 + 0)*PP + rpos)*DD);
  ushort* uws = (ushort*)(ws + FLOAT_END);
  int t = threadIdx.x;
  float4 h = src[t];
  ushort4 h4, l4;
  split4(h, h4, l4);
  *(ushort4*)(uws + U_SIMH_HI + (size_t)idx*DD + t*4) = h4;
  *(ushort4*)(uws + U_SIMH_HI + SIMH_DELTA + (size_t)idx*DD + t*4) = l4;
  float4 a = rt[t], c = rs[t];
  float r1 = block_sum256(dot4(h, h), sb);
  float r2 = block_sum256(dot4(h, a), sb);
  float r3 = block_sum256(dot4(h, c), sb);
  if (t == 0) { ws[OFF_HH + idx] = r1; ws[OFF_RH_T + idx] = r2; ws[OFF_RH_S + idx] = r3; }
}

// ---- main fused kernel: barrier-free K-loop, direct global MFMA fragments ----
// A rows (192): [0..127] sim_high, [128..159] ref_t, [160..191] ref_s
// B cols (64):  [0..31] sh_t(s0+sl), [32..63] sh_s(s0+sl).  BK=32.
// Block map: d = q*24 + u; u -> (z, r-half) pinned to XCD u%8; q -> (r_loc, s_t).
// Fragment loads are 64B-coalesced per row-quad (lanes l15,l15+16,.. read one row).
__global__ __launch_bounds__(256) void k_main(float* __restrict__ ws,
                                              double* __restrict__ acc_out) {
  __shared__ float Csp[192][33];   // 2-pass C staging (25 KB)
  __shared__ float sb[4];
  const char* U = (const char*)(ws + FLOAT_END);

  int d = blockIdx.x;
  int u = d % 24, q = d / 24;
  int z = u >> 1;
  int r_t = (u & 1)*4 + (q >> 3);
  int s_t = q & 7;
  int b = z & 3;
  int s0 = s_t*32, r0 = r_t*32;
  int tid = threadIdx.x;
  int w = tid >> 6, l15 = tid & 15, lq = (tid >> 4) & 3;

  // per-thread global BYTE offsets into U (fit in 32 bits; ws < 68 MB)
  unsigned aoh[3], aol[3], boh[4], bol[4];
#pragma unroll
  for (int i = 0; i < 3; ++i) {
    int G = 3*w + i;
    unsigned row, hi_base, delta;
    if (G < 8)       { row = (unsigned)((b*RR + r0)*4 + G*16 + l15);       hi_base = (unsigned)U_SIMH_HI;  delta = (unsigned)SIMH_DELTA; }
    else if (G < 10) { row = (unsigned)(b*RR + r0 + (G-8)*16 + l15);       hi_base = (unsigned)U_REF_T_HI; delta = (unsigned)REF_DELTA; }
    else             { row = (unsigned)(b*RR + r0 + (G-10)*16 + l15);      hi_base = (unsigned)U_REF_S_HI; delta = (unsigned)REF_DELTA; }
    aoh[i] = 2u*(hi_base + row*1024u) + (unsigned)(lq*16);
    aol[i] = aoh[i] + 2u*delta;
  }
#pragma unroll
  for (int j = 0; j < 4; ++j) {
    unsigned srow = (unsigned)(z*SSZ + s0 + (j & 1)*16 + l15);
    unsigned hb = (j < 2) ? (unsigned)U_SH_T_HI : (unsigned)U_SH_S_HI;
    unsigned lb = (j < 2) ? (unsigned)U_SH_T_LO : (unsigned)U_SH_S_LO;
    boh[j] = 2u*(hb + srow*1024u) + (unsigned)(lq*16);
    bol[j] = 2u*(lb + srow*1024u) + (unsigned)(lq*16);
  }

  f32x4 acc[3][4];
#pragma unroll
  for (int i = 0; i < 3; ++i)
#pragma unroll
    for (int j = 0; j < 4; ++j) acc[i][j] = (f32x4){0.f, 0.f, 0.f, 0.f};

#pragma unroll 2
  for (int kb = 0; kb < 2048; kb += 64) {    // 64 B = 32 bf16 per K-step
    short8 ah[3], al[3];
#pragma unroll
    for (int i = 0; i < 3; ++i) {
      ah[i] = *(const short8*)(U + aoh[i] + kb);
      al[i] = *(const short8*)(U + aol[i] + kb);
    }
#pragma unroll
    for (int j = 0; j < 4; ++j) {
      short8 bh = *(const short8*)(U + boh[j] + kb);
      short8 bl = *(const short8*)(U + bol[j] + kb);
#pragma unroll
      for (int i = 0; i < 3; ++i) {
        acc[i][j] = MFMA16(ah[i], bh, acc[i][j]);
        acc[i][j] = MFMA16(ah[i], bl, acc[i][j]);
        acc[i][j] = MFMA16(al[i], bh, acc[i][j]);
      }
    }
  }

  // epilogue scalars (s-independent)
  int rl = tid >> 3, sg = tid & 7;
  int r = r0 + rl;
  float rrt = ws[OFF_RR_T + b*RR + r];
  float rrs = ws[OFF_RR_S + b*RR + r];
  float hhk[4], rhtk[4], rhsk[4], ihr_t[4], ihr_s[4];
#pragma unroll
  for (int k = 0; k < 4; ++k) {
    int idx = (b*RR + r)*KT + k;
    hhk[k]  = ws[OFF_HH + idx];
    rhtk[k] = ws[OFF_RH_T + idx];
    rhsk[k] = ws[OFF_RH_S + idx];
    float nt = sqrtf(fmaxf(hhk[k] - 2.f*rhtk[k] + rrt, 0.f));
    float ns = sqrtf(fmaxf(hhk[k] - 2.f*rhsk[k] + rrs, 0.f));
    ihr_t[k] = 1.f / fmaxf(nt, 1e-8f);
    ihr_s[k] = 1.f / fmaxf(ns, 1e-8f);
  }

  float local = 0.f;
#pragma unroll
  for (int h = 0; h < 2; ++h) {     // 2 passes x 16 s-columns
    __syncthreads();                // pass 1: previous reads done (no-op cost pass 0)
#pragma unroll
    for (int i = 0; i < 3; ++i)
#pragma unroll
      for (int qq = 0; qq < 4; ++qq) {
        Csp[(3*w + i)*16 + lq*4 + qq][l15]      = acc[i][h][qq];       // t-side col
        Csp[(3*w + i)*16 + lq*4 + qq][16 + l15] = acc[i][2 + h][qq];   // s-side col
      }
    __syncthreads();
#pragma unroll
    for (int jj = 0; jj < 2; ++jj) {
      int tcol = sg*2 + jj;
      int sidx = z*SSZ + s0 + h*16 + tcol;
      float sst = ws[OFF_SS_T + sidx];
      float sss = ws[OFF_SS_S + sidx];
      float srt = Csp[128 + rl][tcol];
      float srs = Csp[160 + rl][16 + tcol];
      float isr_t = 1.f / fmaxf(sqrtf(fmaxf(sst - 2.f*srt + rrt, 0.f)), 1e-8f);
      float isr_s = 1.f / fmaxf(sqrtf(fmaxf(sss - 2.f*srs + rrs, 0.f)), 1e-8f);
#pragma unroll
      for (int k = 0; k < 4; ++k) {
        float sht = Csp[rl*4 + k][tcol];
        float shs = Csp[rl*4 + k][16 + tcol];
        float ish_t = 1.f / fmaxf(sqrtf(fmaxf(sst - 2.f*sht + hhk[k], 0.f)), 1e-8f);
        float ish_s = 1.f / fmaxf(sqrtf(fmaxf(sss - 2.f*shs + hhk[k], 0.f)), 1e-8f);
        float a1t = (sht - rhtk[k] - srt + rrt) * (isr_t * ihr_t[k]);
        float a2t = (srt - sht - rhtk[k] + hhk[k]) * (ihr_t[k] * ish_t);
        float a3t = (rhtk[k] - srt - sht + sst) * (isr_t * ish_t);
        float a1s = (shs - rhsk[k] - srs + rrs) * (isr_s * ihr_s[k]);
        float a2s = (srs - shs - rhsk[k] + hhk[k]) * (ihr_s[k] * ish_s);
        float a3s = (rhsk[k] - srs - shs + sss) * (isr_s * ish_s);
        local += fabsf(a1s - a1t) + fabsf(a2s - a2t) + fabsf(a3s - a3t);
      }
    }
  }
  float tot = block_sum256(local, sb);
  if (tid == 0) atomicAdd(acc_out, (double)tot);
}

__global__ void k_final(const double* __restrict__ acc, float* __restrict__ out) {
  out[0] = (float)(acc[0] / 3145728.0);   // 3 * B * R * S * K
}

extern "C" void kernel_launch(void* const* d_in, const int* in_sizes, int n_in,
                              void* d_out, int out_size, void* d_ws, size_t ws_size,
                              hipStream_t stream) {
  const float* T  = (const float*)d_in[0];
  const float* Sf = (const float*)d_in[1];
  const int* ref_perm    = (const int*)d_in[2];
  const int* shared_perm = (const int*)d_in[3];
  float* ws = (float*)d_ws;
  double* acc = (double*)(ws + OFF_ACC);

  hipMemsetAsync(acc, 0, sizeof(double), stream);
  k_gather_ref<<<BB*RR, 256, 0, stream>>>(T, Sf, ref_perm, ws);
  k_ne<<<BB*EE, 256, 0, stream>>>(T, ws);
  k_ss<<<NPAIR*BB*SSZ, 256, 0, stream>>>(T, Sf, shared_perm, ws);
  dim3 g1(EE/64, RR/64, BB);
  k_sim<<<g1, 256, 0, stream>>>(T, ws);
  k_topk<<<BB*RR, 256, 0, stream>>>(ws);
  k_gather_high<<<BB*RR*KT, 256, 0, stream>>>(T, Sf, ref_perm, ws);
  k_main<<<768, 256, 0, stream>>>(ws, acc);
  k_final<<<1, 1, 0, stream>>>(acc, (float*)d_out);
}

// Round 10
// 194.844 us; speedup vs baseline: 1.3909x; 1.3909x over previous
//
#include <hip/hip_runtime.h>
#include <float.h>

#define BB 4
#define PP 1024
#define DD 1024
#define RR 256
#define SSZ 256
#define KT 4
#define EE 4096
#define NPAIR 3

typedef float  f32x4  __attribute__((ext_vector_type(4)));
typedef short  short8 __attribute__((ext_vector_type(8)));

#define MFMA16(a,b,c) __builtin_amdgcn_mfma_f32_16x16x32_bf16((a),(b),(c),0,0,0)

// ---- float-region offsets (in floats) ----
#define OFF_NE    ((size_t)0)         // BB*EE
#define OFF_RR_T  ((size_t)16384)     // BB*RR
#define OFF_RR_S  ((size_t)17408)
#define OFF_HH    ((size_t)18432)     // BB*RR*KT
#define OFF_RH_T  ((size_t)22528)
#define OFF_RH_S  ((size_t)26624)
#define OFF_SS_T  ((size_t)30720)     // NPAIR*BB*SSZ
#define OFF_SS_S  ((size_t)33792)
#define OFF_TOPK  ((size_t)36864)     // BB*RR*KT ints
#define OFF_ACC   ((size_t)40960)     // double
#define OFF_CAND  ((size_t)45056)     // BB*RR*64*4 float2 = 524288 floats
#define FLOAT_END ((size_t)569344)

// ---- ushort (bf16 hi) region offsets (in ushorts), base = ws + FLOAT_END ----
#define U_REF_T ((size_t)0)           // BB*RR*DD
#define U_REF_S ((size_t)2097152)
#define U_SIMH  ((size_t)4194304)     // BB*RR*KT*DD
#define U_SH_T  ((size_t)8388608)     // NPAIR*BB*SSZ*DD
#define U_SH_S  ((size_t)11534336)
#define U_EXT   ((size_t)14680064)    // BB*EE*DD
// end 31457280 ushorts; total ws ~65.2 MB

__device__ inline float block_sum256(float v, float* sb) {
  v += __shfl_down(v, 32); v += __shfl_down(v, 16);
  v += __shfl_down(v, 8);  v += __shfl_down(v, 4);
  v += __shfl_down(v, 2);  v += __shfl_down(v, 1);
  int lane = threadIdx.x & 63, wid = threadIdx.x >> 6;
  if (lane == 0) sb[wid] = v;
  __syncthreads();
  float r = 0.f;
  if (threadIdx.x < 4) r = sb[threadIdx.x];
  r += __shfl_down(r, 2); r += __shfl_down(r, 1);
  __syncthreads();
  return r;   // valid on thread 0
}

__device__ inline float dot4(const float4& a, const float4& b) {
  return a.x*b.x + a.y*b.y + a.z*b.z + a.w*b.w;
}

// round-to-nearest-even bf16
__device__ inline unsigned short bhi(float x) {
  unsigned u = __float_as_uint(x);
  return (unsigned short)((u + 0x7fffu + ((u >> 16) & 1u)) >> 16);
}
__device__ inline ushort4 h4of(float4 f) {
  return make_ushort4(bhi(f.x), bhi(f.y), bhi(f.z), bhi(f.w));
}

// ---- gather ref rows: norms + bf16 store ----
__global__ __launch_bounds__(256) void k_gather_ref(const float* __restrict__ T,
                                                    const float* __restrict__ Sf,
                                                    const int* __restrict__ ref_perm,
                                                    float* __restrict__ ws) {
  __shared__ float sb[4];
  int b = blockIdx.x >> 8, r = blockIdx.x & 255;
  int pos = ref_perm[r];
  const float4* ts = (const float4*)(T  + ((size_t)(b*8 + 0)*PP + pos)*DD);
  const float4* sv = (const float4*)(Sf + ((size_t)(b*4 + 0)*PP + pos)*DD);
  ushort* uws = (ushort*)(ws + FLOAT_END);
  int t = threadIdx.x;
  float4 a = ts[t], c = sv[t];
  size_t base = ((size_t)b*RR + r)*DD + t*4;
  *(ushort4*)(uws + U_REF_T + base) = h4of(a);
  *(ushort4*)(uws + U_REF_S + base) = h4of(c);
  float r1 = block_sum256(dot4(a, a), sb);
  float r2 = block_sum256(dot4(c, c), sb);
  if (t == 0) {
    ws[OFF_RR_T + b*RR + r] = r1;
    ws[OFF_RR_S + b*RR + r] = r2;
  }
}

// ---- extra rows: clamped norms + bf16 conversion ----
__global__ __launch_bounds__(256) void k_ne(const float* __restrict__ T, float* __restrict__ ws) {
  __shared__ float sb[4];
  int b = blockIdx.x >> 12, e = blockIdx.x & 4095;
  int f = 1 + 2*(e >> 10);
  int pos = e & 1023;
  const float4* src = (const float4*)(T + ((size_t)(b*8 + f)*PP + pos)*DD);
  ushort* uws = (ushort*)(ws + FLOAT_END);
  int t = threadIdx.x;
  float4 a = src[t];
  *(ushort4*)(uws + U_EXT + ((size_t)b*EE + e)*DD + t*4) = h4of(a);
  float tot = block_sum256(dot4(a, a), sb);
  if (t == 0) ws[OFF_NE + (size_t)b*EE + e] = fmaxf(sqrtf(tot), 1e-12f);
}

// ---- shared rows: norms + bf16 store ----
__global__ __launch_bounds__(256) void k_ss(const float* __restrict__ T,
                                            const float* __restrict__ Sf,
                                            const int* __restrict__ shared_perm,
                                            float* __restrict__ ws) {
  __shared__ float sb[4];
  int idx = blockIdx.x;                  // z*SSZ + s
  int p = idx / (BB*SSZ);
  int b = (idx / SSZ) % BB;
  int s = idx % SSZ;
  int pos = shared_perm[s];
  int ti = 2*(p + 1), si = p + 1;
  const float4* tr = (const float4*)(T  + ((size_t)(b*8 + ti)*PP + pos)*DD);
  const float4* sr = (const float4*)(Sf + ((size_t)(b*4 + si)*PP + pos)*DD);
  ushort* uws = (ushort*)(ws + FLOAT_END);
  int t = threadIdx.x;
  float4 a = tr[t], c = sr[t];
  size_t base = (size_t)idx*DD + t*4;
  *(ushort4*)(uws + U_SH_T + base) = h4of(a);
  *(ushort4*)(uws + U_SH_S + base) = h4of(c);
  float r1 = block_sum256(dot4(a, a), sb);
  float r2 = block_sum256(dot4(c, c), sb);
  if (t == 0) { ws[OFF_SS_T + idx] = r1; ws[OFF_SS_S + idx] = r2; }
}

// ---- sim GEMM (single bf16) + fused per-block top-4 over 64 e's ----
__global__ __launch_bounds__(256) void k_sim(float* __restrict__ ws) {
  __shared__ union SM {
    struct { ushort Ah[64][40]; ushort Bh[64][40]; } s;
    float simv[64][68];
  } sm;
  const ushort* uws = (const ushort*)(ws + FLOAT_END);
  int e0 = blockIdx.x * 64, r0 = blockIdx.y * 64, b = blockIdx.z;
  int tid = threadIdx.x;
  int srow = tid >> 2, sch = (tid & 3) * 8;
  const ushort* pA = uws + U_REF_T + ((size_t)(b*RR + r0 + srow))*DD + sch;
  const ushort* pB = uws + U_EXT + ((size_t)(b*EE + e0 + srow))*DD + sch;
  int w = tid >> 6, l15 = tid & 15, lq = (tid >> 4) & 3, lk8 = lq*8;
  f32x4 acc[4];
#pragma unroll
  for (int j = 0; j < 4; ++j) acc[j] = (f32x4){0.f, 0.f, 0.f, 0.f};

#pragma unroll 1
  for (int k0 = 0; k0 < DD; k0 += 32) {
    uint4 va = *(const uint4*)(pA + k0);
    uint4 vb = *(const uint4*)(pB + k0);
    __syncthreads();
    *(uint4*)&sm.s.Ah[srow][sch] = va;
    *(uint4*)&sm.s.Bh[srow][sch] = vb;
    __syncthreads();
    short8 ah = *(const short8*)&sm.s.Ah[w*16 + l15][lk8];
#pragma unroll
    for (int j = 0; j < 4; ++j) {
      short8 bh = *(const short8*)&sm.s.Bh[j*16 + l15][lk8];
      acc[j] = MFMA16(ah, bh, acc[j]);
    }
  }
  __syncthreads();   // done with Ah/Bh reads, reuse as simv
#pragma unroll
  for (int j = 0; j < 4; ++j) {
    int e_loc = j*16 + l15;
    float inv = 1.f / ws[OFF_NE + (size_t)b*EE + e0 + e_loc];
#pragma unroll
    for (int q = 0; q < 4; ++q)
      sm.simv[w*16 + lq*4 + q][e_loc] = acc[j][q] * inv;
  }
  __syncthreads();
  if (tid < 64) {
    float v[4] = {-FLT_MAX, -FLT_MAX, -FLT_MAX, -FLT_MAX};
    int ix[4] = {0x7fffffff, 0x7fffffff, 0x7fffffff, 0x7fffffff};
#pragma unroll 1
    for (int e = 0; e < 64; ++e) {
      float f = sm.simv[tid][e];
      if (f > v[3]) {
        int eg = e0 + e;
        if (f > v[0])      { v[3]=v[2]; ix[3]=ix[2]; v[2]=v[1]; ix[2]=ix[1]; v[1]=v[0]; ix[1]=ix[0]; v[0]=f; ix[0]=eg; }
        else if (f > v[1]) { v[3]=v[2]; ix[3]=ix[2]; v[2]=v[1]; ix[2]=ix[1]; v[1]=f; ix[1]=eg; }
        else if (f > v[2]) { v[3]=v[2]; ix[3]=ix[2]; v[2]=f; ix[2]=eg; }
        else               { v[3]=f; ix[3]=eg; }
      }
    }
    float2* cand = (float2*)(ws + OFF_CAND);
    size_t base = (((size_t)(b*RR + r0 + tid))*64 + blockIdx.x)*4;
#pragma unroll
    for (int k = 0; k < 4; ++k)
      cand[base + k] = make_float2(v[k], __int_as_float(ix[k]));
  }
}

// ---- merge 256 candidates -> top-4 per (b,r), ties -> lower global index ----
__global__ __launch_bounds__(256) void k_topk2(float* __restrict__ ws) {
  __shared__ float rv[256];
  __shared__ int   ri[256];
  __shared__ int   winIdx;
  int br = blockIdx.x;
  int tid = threadIdx.x;
  const float2* cand = (const float2*)(ws + OFF_CAND);
  float2 c = cand[(size_t)br*256 + tid];
  float v = c.x;
  int idx = __float_as_int(c.y);
  int* outi = (int*)(ws + OFF_TOPK) + (size_t)br*KT;
  for (int k = 0; k < KT; ++k) {
    rv[tid] = v; ri[tid] = idx;
    __syncthreads();
    for (int off = 128; off > 0; off >>= 1) {
      if (tid < off) {
        float v2 = rv[tid+off]; int i2 = ri[tid+off];
        if (v2 > rv[tid] || (v2 == rv[tid] && i2 < ri[tid])) { rv[tid] = v2; ri[tid] = i2; }
      }
      __syncthreads();
    }
    if (tid == 0) { outi[k] = ri[0]; winIdx = ri[0]; }
    __syncthreads();
    if (idx == winIdx) v = -FLT_MAX;
    __syncthreads();
  }
}

// ---- gather selected rows: bf16 store + hh / rh_t / rh_s (fp32) ----
__global__ __launch_bounds__(256) void k_gather_high(const float* __restrict__ T,
                                                     const float* __restrict__ Sf,
                                                     const int* __restrict__ ref_perm,
                                                     float* __restrict__ ws) {
  __shared__ float sb[4];
  int idx = blockIdx.x;                        // (b*RR + r)*KT + k
  int e = ((const int*)(ws + OFF_TOPK))[idx];
  int b = idx >> 10;
  int r = (idx >> 2) & 255;
  int rpos = ref_perm[r];
  const float4* src = (const float4*)(T + ((size_t)(b*8 + 1 + 2*(e >> 10))*PP + (e & 1023))*DD);
  const float4* rt  = (const float4*)(T  + ((size_t)(b*8 + 0)*PP + rpos)*DD);
  const float4* rs  = (const float4*)(Sf + ((size_t)(b*4 + 0)*PP + rpos)*DD);
  ushort* uws = (ushort*)(ws + FLOAT_END);
  int t = threadIdx.x;
  float4 h = src[t];
  *(ushort4*)(uws + U_SIMH + (size_t)idx*DD + t*4) = h4of(h);
  float4 a = rt[t], c = rs[t];
  float r1 = block_sum256(dot4(h, h), sb);
  float r2 = block_sum256(dot4(h, a), sb);
  float r3 = block_sum256(dot4(h, c), sb);
  if (t == 0) { ws[OFF_HH + idx] = r1; ws[OFF_RH_T + idx] = r2; ws[OFF_RH_S + idx] = r3; }
}

// ---- main fused kernel: 512 threads, single-bf16, LDS-staged, XCD-grouped ----
// A rows (192): [0..127] sim_high, [128..159] ref_t, [160..191] ref_s
// B rows (64):  [0..31] sh_t(s0+..), [32..63] sh_s.  BK=32.
// Wave w: mw=w&3 -> A-frag rows (3mw..3mw+2)*16; nh=w>>2 -> B side (0=t,1=s), frags j=0..1.
__global__ __launch_bounds__(512) void k_main(float* __restrict__ ws,
                                              double* __restrict__ acc_out) {
  __shared__ union SM {
    ushort stg[256][40];
    struct { float Ct[192][17]; float Cs2[192][17]; } c;
  } sm;
  __shared__ float sb[8];
  const ushort* uws = (const ushort*)(ws + FLOAT_END);

  int d = blockIdx.x;
  int u = d % 24, q = d / 24;
  int z = u >> 1;
  int b = z & 3;
  int r_t = (u & 1)*4 + (q >> 3);
  int s_t = q & 7;
  int s0 = s_t*32, r0 = r_t*32;
  int tid = threadIdx.x;
  int w = tid >> 6, l15 = tid & 15, lq = (tid >> 4) & 3;
  int mw = w & 3, nh = w >> 2;

  // staging: 1024 slots (16 groups x 16 rows x 4 chunks), 2 per thread
  const ushort* src[2];
  int dst[2];
#pragma unroll
  for (int t2 = 0; t2 < 2; ++t2) {
    int s = tid + t2*512;
    int g = s >> 6, i = s & 63, row = i & 15, ch = i >> 4;
    const ushort* base; size_t rowg;
    if (g < 8)       { base = uws + U_SIMH;  rowg = (size_t)((b*RR + r0)*4 + g*16 + row); }
    else if (g < 10) { base = uws + U_REF_T; rowg = (size_t)(b*RR + r0 + (g-8)*16 + row); }
    else if (g < 12) { base = uws + U_REF_S; rowg = (size_t)(b*RR + r0 + (g-10)*16 + row); }
    else if (g < 14) { base = uws + U_SH_T;  rowg = (size_t)(z*SSZ + s0 + (g-12)*16 + row); }
    else             { base = uws + U_SH_S;  rowg = (size_t)(z*SSZ + s0 + (g-14)*16 + row); }
    src[t2] = base + rowg*DD + ch*8;
    int R = (g < 12) ? (g*16 + row) : (192 + (g-12)*16 + row);
    dst[t2] = R*40 + ch*8;
  }
  ushort* L = &sm.stg[0][0];

  f32x4 acc[3][2];
#pragma unroll
  for (int i = 0; i < 3; ++i)
#pragma unroll
    for (int j = 0; j < 2; ++j) acc[i][j] = (f32x4){0.f, 0.f, 0.f, 0.f};

#pragma unroll 1
  for (int k0 = 0; k0 < DD; k0 += 32) {
    uint4 v0 = *(const uint4*)(src[0] + k0);
    uint4 v1 = *(const uint4*)(src[1] + k0);
    __syncthreads();
    *(uint4*)(L + dst[0]) = v0;
    *(uint4*)(L + dst[1]) = v1;
    __syncthreads();
    short8 ah[3], bh[2];
#pragma unroll
    for (int i = 0; i < 3; ++i)
      ah[i] = *(const short8*)&sm.stg[(3*mw + i)*16 + l15][lq*8];
#pragma unroll
    for (int j = 0; j < 2; ++j)
      bh[j] = *(const short8*)&sm.stg[192 + nh*32 + j*16 + l15][lq*8];
#pragma unroll
    for (int j = 0; j < 2; ++j)
#pragma unroll
      for (int i = 0; i < 3; ++i)
        acc[i][j] = MFMA16(ah[i], bh[j], acc[i][j]);
  }

  // epilogue scalars
  int rl = tid >> 4, sl = tid & 15;   // rl 0..31, sl 0..15
  int r = r0 + rl;
  float rrt = ws[OFF_RR_T + b*RR + r];
  float rrs = ws[OFF_RR_S + b*RR + r];
  float hhk[4], rhtk[4], rhsk[4], ihr_t[4], ihr_s[4];
#pragma unroll
  for (int k = 0; k < 4; ++k) {
    int idx = (b*RR + r)*KT + k;
    hhk[k]  = ws[OFF_HH + idx];
    rhtk[k] = ws[OFF_RH_T + idx];
    rhsk[k] = ws[OFF_RH_S + idx];
    float nt = sqrtf(fmaxf(hhk[k] - 2.f*rhtk[k] + rrt, 0.f));
    float ns = sqrtf(fmaxf(hhk[k] - 2.f*rhsk[k] + rrs, 0.f));
    ihr_t[k] = 1.f / fmaxf(nt, 1e-8f);
    ihr_s[k] = 1.f / fmaxf(ns, 1e-8f);
  }

  float local = 0.f;
#pragma unroll
  for (int h = 0; h < 2; ++h) {
    __syncthreads();                 // prior LDS reads done
#pragma unroll
    for (int i = 0; i < 3; ++i)
#pragma unroll
      for (int qq = 0; qq < 4; ++qq) {
        int row = (3*mw + i)*16 + lq*4 + qq;
        if (nh == 0) sm.c.Ct[row][l15]  = acc[i][h][qq];
        else         sm.c.Cs2[row][l15] = acc[i][h][qq];
      }
    __syncthreads();
    int sidx = z*SSZ + s0 + h*16 + sl;
    float sst = ws[OFF_SS_T + sidx];
    float sss = ws[OFF_SS_S + sidx];
    float srt = sm.c.Ct[128 + rl][sl];
    float srs = sm.c.Cs2[160 + rl][sl];
    float isr_t = 1.f / fmaxf(sqrtf(fmaxf(sst - 2.f*srt + rrt, 0.f)), 1e-8f);
    float isr_s = 1.f / fmaxf(sqrtf(fmaxf(sss - 2.f*srs + rrs, 0.f)), 1e-8f);
#pragma unroll
    for (int k = 0; k < 4; ++k) {
      float sht = sm.c.Ct[rl*4 + k][sl];
      float shs = sm.c.Cs2[rl*4 + k][sl];
      float ish_t = 1.f / fmaxf(sqrtf(fmaxf(sst - 2.f*sht + hhk[k], 0.f)), 1e-8f);
      float ish_s = 1.f / fmaxf(sqrtf(fmaxf(sss - 2.f*shs + hhk[k], 0.f)), 1e-8f);
      float a1t = (sht - rhtk[k] - srt + rrt) * (isr_t * ihr_t[k]);
      float a2t = (srt - sht - rhtk[k] + hhk[k]) * (ihr_t[k] * ish_t);
      float a3t = (rhtk[k] - srt - sht + sst) * (isr_t * ish_t);
      float a1s = (shs - rhsk[k] - srs + rrs) * (isr_s * ihr_s[k]);
      float a2s = (srs - shs - rhsk[k] + hhk[k]) * (ihr_s[k] * ish_s);
      float a3s = (rhsk[k] - srs - shs + sss) * (isr_s * ish_s);
      local += fabsf(a1s - a1t) + fabsf(a2s - a2t) + fabsf(a3s - a3t);
    }
  }

  // block sum over 512 threads
  float v = local;
  v += __shfl_down(v, 32); v += __shfl_down(v, 16);
  v += __shfl_down(v, 8);  v += __shfl_down(v, 4);
  v += __shfl_down(v, 2);  v += __shfl_down(v, 1);
  if ((tid & 63) == 0) sb[w] = v;
  __syncthreads();
  if (tid < 8) {
    float rsum = sb[tid];
    rsum += __shfl_down(rsum, 4);
    rsum += __shfl_down(rsum, 2);
    rsum += __shfl_down(rsum, 1);
    if (tid == 0) atomicAdd(acc_out, (double)rsum);
  }
}

__global__ void k_final(const double* __restrict__ acc, float* __restrict__ out) {
  out[0] = (float)(acc[0] / 3145728.0);   // 3 * B * R * S * K
}

extern "C" void kernel_launch(void* const* d_in, const int* in_sizes, int n_in,
                              void* d_out, int out_size, void* d_ws, size_t ws_size,
                              hipStream_t stream) {
  const float* T  = (const float*)d_in[0];
  const float* Sf = (const float*)d_in[1];
  const int* ref_perm    = (const int*)d_in[2];
  const int* shared_perm = (const int*)d_in[3];
  float* ws = (float*)d_ws;
  double* acc = (double*)(ws + OFF_ACC);

  hipMemsetAsync(acc, 0, sizeof(double), stream);
  k_gather_ref<<<BB*RR, 256, 0, stream>>>(T, Sf, ref_perm, ws);
  k_ne<<<BB*EE, 256, 0, stream>>>(T, ws);
  k_ss<<<NPAIR*BB*SSZ, 256, 0, stream>>>(T, Sf, shared_perm, ws);
  dim3 g1(EE/64, RR/64, BB);
  k_sim<<<g1, 256, 0, stream>>>(ws);
  k_topk2<<<BB*RR, 256, 0, stream>>>(ws);
  k_gather_high<<<BB*RR*KT, 256, 0, stream>>>(T, Sf, ref_perm, ws);
  k_main<<<768, 512, 0, stream>>>(ws, acc);
  k_final<<<1, 1, 0, stream>>>(acc, (float*)d_out);
}